// Round 1
// baseline (624.547 us; speedup 1.0000x reference)
//
#include <hip/hip_runtime.h>
#include <math.h>

#define THREADS 256
#define NWAVES (THREADS / 64)

// One block per batch row b.
// d_in: [0] receiver_output (B,E) f32, [1] emb (V,E) f32, [2] nns (V,Knns) i32,
//       [3] labels (B,) i32, [4] num_hard_negatives scalar i32
// d_out: loss (B,) f32 then acc (B,) f32.
__global__ __launch_bounds__(THREADS) void disc_loss_kernel(
    const float* __restrict__ ro_g,
    const float* __restrict__ emb,
    const int* __restrict__ nns,
    const int* __restrict__ labels,
    const int* __restrict__ nhn_ptr,
    float* __restrict__ loss_out,
    float* __restrict__ acc_out,
    int E, int Knns)
{
    const int b    = blockIdx.x;
    const int tid  = threadIdx.x;
    const int lane = tid & 63;
    const int wave = tid >> 6;
    const int K    = nhn_ptr[0] + 1;   // 128
    const int E4   = E >> 2;

    extern __shared__ char smem_raw[];
    float* s_ro     = (float*)smem_raw;             // E floats
    float* s_scores = s_ro + E;                     // Knns floats
    int*   s_nns    = (int*)(s_scores + Knns);      // Knns ints
    __shared__ float s_sum[NWAVES], s_max[NWAVES];
    __shared__ float s_invnorm;

    // ---- Pass 1: stage receiver row in LDS; fused sumsq + rowmax ----
    const float4* ro4   = (const float4*)(ro_g + (size_t)b * E);
    float4*       s_ro4 = (float4*)s_ro;
    float lsum = 0.f, lmax = -INFINITY;
    for (int i = tid; i < E4; i += THREADS) {
        float4 v = ro4[i];
        s_ro4[i] = v;
        lsum += v.x * v.x + v.y * v.y + v.z * v.z + v.w * v.w;
        lmax = fmaxf(lmax, fmaxf(fmaxf(v.x, v.y), fmaxf(v.z, v.w)));
    }

    // Stage this row's neighbor ids.
    const int label = labels[b];
    const int* nrow = nns + (size_t)label * Knns;
    for (int i = tid; i < K; i += THREADS) s_nns[i] = nrow[i];

    // Wave reduce, then cross-wave combine.
    for (int m = 32; m; m >>= 1) {
        lsum += __shfl_xor(lsum, m, 64);
        lmax = fmaxf(lmax, __shfl_xor(lmax, m, 64));
    }
    if (lane == 0) { s_sum[wave] = lsum; s_max[wave] = lmax; }
    __syncthreads();
    if (tid == 0) {
        float t = 0.f, mx = -INFINITY;
        for (int w = 0; w < NWAVES; ++w) { t += s_sum[w]; mx = fmaxf(mx, s_max[w]); }
        s_invnorm = 1.0f / sqrtf(t);
        // argmax(ro_normalized)==0  <=>  ro[b,0] >= rowmax (first-occurrence ties -> idx 0)
        acc_out[b] = (s_ro[0] >= mx) ? 1.0f : 0.0f;
    }
    __syncthreads();
    const float invn = s_invnorm;

    // ---- Pass 2: per-wave neighbor dot products (unroll 2 neighbors) ----
    for (int n = wave; n < K; n += 2 * NWAVES) {
        const int n1   = n + NWAVES;
        const int idx0 = s_nns[n];
        const int idx1 = (n1 < K) ? s_nns[n1] : idx0;
        const float4* e0 = (const float4*)(emb + (size_t)idx0 * E);
        const float4* e1 = (const float4*)(emb + (size_t)idx1 * E);

        float acc0 = 0.f, acc1 = 0.f;
        int j = lane;
        for (; j + 192 < E4; j += 256) {
            float4 a0 = e0[j], a1 = e0[j + 64], a2 = e0[j + 128], a3 = e0[j + 192];
            float4 b0 = e1[j], b1 = e1[j + 64], b2 = e1[j + 128], b3 = e1[j + 192];
            float4 r0 = s_ro4[j], r1 = s_ro4[j + 64], r2 = s_ro4[j + 128], r3 = s_ro4[j + 192];
            acc0 += a0.x * r0.x + a0.y * r0.y + a0.z * r0.z + a0.w * r0.w;
            acc0 += a1.x * r1.x + a1.y * r1.y + a1.z * r1.z + a1.w * r1.w;
            acc0 += a2.x * r2.x + a2.y * r2.y + a2.z * r2.z + a2.w * r2.w;
            acc0 += a3.x * r3.x + a3.y * r3.y + a3.z * r3.z + a3.w * r3.w;
            acc1 += b0.x * r0.x + b0.y * r0.y + b0.z * r0.z + b0.w * r0.w;
            acc1 += b1.x * r1.x + b1.y * r1.y + b1.z * r1.z + b1.w * r1.w;
            acc1 += b2.x * r2.x + b2.y * r2.y + b2.z * r2.z + b2.w * r2.w;
            acc1 += b3.x * r3.x + b3.y * r3.y + b3.z * r3.z + b3.w * r3.w;
        }
        for (; j < E4; j += 64) {   // remainder (E not multiple of 1024)
            float4 a = e0[j], c = e1[j], r = s_ro4[j];
            acc0 += a.x * r.x + a.y * r.y + a.z * r.z + a.w * r.w;
            acc1 += c.x * r.x + c.y * r.y + c.z * r.z + c.w * r.w;
        }
        for (int m = 32; m; m >>= 1) {
            acc0 += __shfl_xor(acc0, m, 64);
            acc1 += __shfl_xor(acc1, m, 64);
        }
        if (lane == 0) {
            s_scores[n] = acc0 * invn;
            if (n1 < K) s_scores[n1] = acc1 * invn;
        }
    }
    __syncthreads();

    // ---- Softmax over K scores on wave 0; loss = m + log(sum exp) - s0 ----
    if (wave == 0) {
        float v0 = (lane < K) ? s_scores[lane] : -INFINITY;
        float v1 = (lane + 64 < K) ? s_scores[lane + 64] : -INFINITY;
        float m = fmaxf(v0, v1);
        for (int mm = 32; mm; mm >>= 1) m = fmaxf(m, __shfl_xor(m, mm, 64));
        float e = ((lane < K) ? expf(v0 - m) : 0.f) +
                  ((lane + 64 < K) ? expf(v1 - m) : 0.f);
        for (int mm = 32; mm; mm >>= 1) e += __shfl_xor(e, mm, 64);
        if (lane == 0) loss_out[b] = logf(e) + m - s_scores[0];
    }
}

extern "C" void kernel_launch(void* const* d_in, const int* in_sizes, int n_in,
                              void* d_out, int out_size, void* d_ws, size_t ws_size,
                              hipStream_t stream) {
    const float* ro     = (const float*)d_in[0];
    const float* emb    = (const float*)d_in[1];
    const int*   nns    = (const int*)d_in[2];
    const int*   labels = (const int*)d_in[3];
    const int*   nhn    = (const int*)d_in[4];

    const int B    = in_sizes[3];                 // 2048
    const int E    = in_sizes[0] / B;             // 1024
    const int V    = in_sizes[1] / E;             // 100000
    const int Knns = in_sizes[2] / V;             // 128

    float* loss_out = (float*)d_out;
    float* acc_out  = loss_out + B;

    size_t smem = (size_t)(E + Knns) * sizeof(float) + (size_t)Knns * sizeof(int);
    disc_loss_kernel<<<dim3(B), dim3(THREADS), smem, stream>>>(
        ro, emb, nns, labels, nhn, loss_out, acc_out, E, Knns);
}

// Round 2
// 622.328 us; speedup vs baseline: 1.0036x; 1.0036x over previous
//
#include <hip/hip_runtime.h>
#include <math.h>

#define THREADS 256
#define NWAVES 4

// One block per batch row. Each wave holds the ENTIRE receiver row in
// registers (NCHUNK float4 per lane, NCHUNK = E/256), so the hot gather loop
// touches no LDS. 4 neighbors per wave-iteration => 16 x 16B loads in flight.
template <int NCHUNK>
__global__ __launch_bounds__(THREADS) void disc_loss_kernel(
    const float* __restrict__ ro_g,
    const float* __restrict__ emb,
    const int* __restrict__ nns,
    const int* __restrict__ labels,
    const int* __restrict__ nhn_ptr,
    float* __restrict__ loss_out,
    float* __restrict__ acc_out,
    int E, int Knns)
{
    const int b    = blockIdx.x;
    const int tid  = threadIdx.x;
    const int lane = tid & 63;
    const int wave = tid >> 6;
    const int K    = nhn_ptr[0] + 1;   // 128

    __shared__ float s_scores[256];
    __shared__ int   s_nns[256];

    // Stage this row's neighbor ids.
    const int  label = labels[b];
    const int* nrow  = nns + (size_t)label * Knns;
    for (int i = tid; i < K; i += THREADS) s_nns[i] = nrow[i];

    // Each wave loads the full receiver row into registers (redundant across
    // waves; 4 KB row, hits L1/L2 for waves 1-3). Fused sumsq + rowmax.
    const float4* ro4 = (const float4*)(ro_g + (size_t)b * E);
    float4 r[NCHUNK];
    float lsum = 0.f, lmax = -INFINITY;
#pragma unroll
    for (int c = 0; c < NCHUNK; ++c) {
        float4 v = ro4[lane + 64 * c];
        r[c] = v;
        lsum += v.x * v.x + v.y * v.y + v.z * v.z + v.w * v.w;
        lmax = fmaxf(lmax, fmaxf(fmaxf(v.x, v.y), fmaxf(v.z, v.w)));
    }
    for (int m = 32; m; m >>= 1) {
        lsum += __shfl_xor(lsum, m, 64);
        lmax = fmaxf(lmax, __shfl_xor(lmax, m, 64));
    }
    const float invn = 1.0f / sqrtf(lsum);   // every wave has it; no barrier
    if (tid == 0)
        acc_out[b] = (ro_g[(size_t)b * E] >= lmax) ? 1.0f : 0.0f;

    __syncthreads();   // s_nns ready

    // ---- Hot loop: 4 neighbors / wave / iteration, register-resident ro ----
    for (int n0 = wave * 4; n0 < K; n0 += NWAVES * 4) {
        const int i0 = s_nns[n0];
        const int i1 = s_nns[(n0 + 1 < K) ? n0 + 1 : n0];
        const int i2 = s_nns[(n0 + 2 < K) ? n0 + 2 : n0];
        const int i3 = s_nns[(n0 + 3 < K) ? n0 + 3 : n0];
        const float4* e0 = (const float4*)(emb + (size_t)i0 * E);
        const float4* e1 = (const float4*)(emb + (size_t)i1 * E);
        const float4* e2 = (const float4*)(emb + (size_t)i2 * E);
        const float4* e3 = (const float4*)(emb + (size_t)i3 * E);

        float a0 = 0.f, a1 = 0.f, a2 = 0.f, a3 = 0.f;
#pragma unroll
        for (int c = 0; c < NCHUNK; ++c) {
            const int j = lane + 64 * c;
            float4 v0 = e0[j], v1 = e1[j], v2 = e2[j], v3 = e3[j];
            float4 rc = r[c];
            a0 += v0.x * rc.x + v0.y * rc.y + v0.z * rc.z + v0.w * rc.w;
            a1 += v1.x * rc.x + v1.y * rc.y + v1.z * rc.z + v1.w * rc.w;
            a2 += v2.x * rc.x + v2.y * rc.y + v2.z * rc.z + v2.w * rc.w;
            a3 += v3.x * rc.x + v3.y * rc.y + v3.z * rc.z + v3.w * rc.w;
        }
        for (int m = 32; m; m >>= 1) {
            a0 += __shfl_xor(a0, m, 64);
            a1 += __shfl_xor(a1, m, 64);
            a2 += __shfl_xor(a2, m, 64);
            a3 += __shfl_xor(a3, m, 64);
        }
        if (lane == 0) {
            s_scores[n0] = a0 * invn;
            if (n0 + 1 < K) s_scores[n0 + 1] = a1 * invn;
            if (n0 + 2 < K) s_scores[n0 + 2] = a2 * invn;
            if (n0 + 3 < K) s_scores[n0 + 3] = a3 * invn;
        }
    }
    __syncthreads();

    // ---- Softmax over K scores on wave 0; loss = m + log(sum exp) - s0 ----
    if (wave == 0) {
        float v0 = (lane < K) ? s_scores[lane] : -INFINITY;
        float v1 = (lane + 64 < K) ? s_scores[lane + 64] : -INFINITY;
        float m = fmaxf(v0, v1);
        for (int mm = 32; mm; mm >>= 1) m = fmaxf(m, __shfl_xor(m, mm, 64));
        float e = ((lane < K) ? expf(v0 - m) : 0.f) +
                  ((lane + 64 < K) ? expf(v1 - m) : 0.f);
        for (int mm = 32; mm; mm >>= 1) e += __shfl_xor(e, mm, 64);
        if (lane == 0) loss_out[b] = logf(e) + m - s_scores[0];
    }
}

// ---- Generic fallback (E not a multiple of 256): round-0 LDS-staged path ----
__global__ __launch_bounds__(THREADS) void disc_loss_kernel_generic(
    const float* __restrict__ ro_g,
    const float* __restrict__ emb,
    const int* __restrict__ nns,
    const int* __restrict__ labels,
    const int* __restrict__ nhn_ptr,
    float* __restrict__ loss_out,
    float* __restrict__ acc_out,
    int E, int Knns)
{
    const int b    = blockIdx.x;
    const int tid  = threadIdx.x;
    const int lane = tid & 63;
    const int wave = tid >> 6;
    const int K    = nhn_ptr[0] + 1;
    const int E4   = E >> 2;

    extern __shared__ char smem_raw[];
    float* s_ro     = (float*)smem_raw;
    float* s_scores = s_ro + E;
    int*   s_nns    = (int*)(s_scores + Knns);
    __shared__ float s_sum[NWAVES], s_max[NWAVES];
    __shared__ float s_invnorm;

    const float4* ro4   = (const float4*)(ro_g + (size_t)b * E);
    float4*       s_ro4 = (float4*)s_ro;
    float lsum = 0.f, lmax = -INFINITY;
    for (int i = tid; i < E4; i += THREADS) {
        float4 v = ro4[i];
        s_ro4[i] = v;
        lsum += v.x * v.x + v.y * v.y + v.z * v.z + v.w * v.w;
        lmax = fmaxf(lmax, fmaxf(fmaxf(v.x, v.y), fmaxf(v.z, v.w)));
    }
    const int label = labels[b];
    const int* nrow = nns + (size_t)label * Knns;
    for (int i = tid; i < K; i += THREADS) s_nns[i] = nrow[i];
    for (int m = 32; m; m >>= 1) {
        lsum += __shfl_xor(lsum, m, 64);
        lmax = fmaxf(lmax, __shfl_xor(lmax, m, 64));
    }
    if (lane == 0) { s_sum[wave] = lsum; s_max[wave] = lmax; }
    __syncthreads();
    if (tid == 0) {
        float t = 0.f, mx = -INFINITY;
        for (int w = 0; w < NWAVES; ++w) { t += s_sum[w]; mx = fmaxf(mx, s_max[w]); }
        s_invnorm = 1.0f / sqrtf(t);
        acc_out[b] = (s_ro[0] >= mx) ? 1.0f : 0.0f;
    }
    __syncthreads();
    const float invn = s_invnorm;

    for (int n = wave; n < K; n += NWAVES) {
        const int idx = s_nns[n];
        const float4* e = (const float4*)(emb + (size_t)idx * E);
        float acc = 0.f;
        for (int j = lane; j < E4; j += 64) {
            float4 a = e[j], rr = s_ro4[j];
            acc += a.x * rr.x + a.y * rr.y + a.z * rr.z + a.w * rr.w;
        }
        for (int m = 32; m; m >>= 1) acc += __shfl_xor(acc, m, 64);
        if (lane == 0) s_scores[n] = acc * invn;
    }
    __syncthreads();

    if (wave == 0) {
        float v0 = (lane < K) ? s_scores[lane] : -INFINITY;
        float v1 = (lane + 64 < K) ? s_scores[lane + 64] : -INFINITY;
        float m = fmaxf(v0, v1);
        for (int mm = 32; mm; mm >>= 1) m = fmaxf(m, __shfl_xor(m, mm, 64));
        float e = ((lane < K) ? expf(v0 - m) : 0.f) +
                  ((lane + 64 < K) ? expf(v1 - m) : 0.f);
        for (int mm = 32; mm; mm >>= 1) e += __shfl_xor(e, mm, 64);
        if (lane == 0) loss_out[b] = logf(e) + m - s_scores[0];
    }
}

extern "C" void kernel_launch(void* const* d_in, const int* in_sizes, int n_in,
                              void* d_out, int out_size, void* d_ws, size_t ws_size,
                              hipStream_t stream) {
    const float* ro     = (const float*)d_in[0];
    const float* emb    = (const float*)d_in[1];
    const int*   nns    = (const int*)d_in[2];
    const int*   labels = (const int*)d_in[3];
    const int*   nhn    = (const int*)d_in[4];

    const int B    = in_sizes[3];                 // 2048
    const int E    = in_sizes[0] / B;             // 1024
    const int V    = in_sizes[1] / E;             // 100000
    const int Knns = in_sizes[2] / V;             // 128

    float* loss_out = (float*)d_out;
    float* acc_out  = loss_out + B;

    const int nchunk = (E % 256 == 0) ? (E / 256) : 0;
    switch (nchunk) {
        case 1: disc_loss_kernel<1><<<dim3(B), dim3(THREADS), 0, stream>>>(
                    ro, emb, nns, labels, nhn, loss_out, acc_out, E, Knns); break;
        case 2: disc_loss_kernel<2><<<dim3(B), dim3(THREADS), 0, stream>>>(
                    ro, emb, nns, labels, nhn, loss_out, acc_out, E, Knns); break;
        case 4: disc_loss_kernel<4><<<dim3(B), dim3(THREADS), 0, stream>>>(
                    ro, emb, nns, labels, nhn, loss_out, acc_out, E, Knns); break;
        case 8: disc_loss_kernel<8><<<dim3(B), dim3(THREADS), 0, stream>>>(
                    ro, emb, nns, labels, nhn, loss_out, acc_out, E, Knns); break;
        default: {
            size_t smem = (size_t)(E + Knns) * sizeof(float) + (size_t)Knns * sizeof(int);
            disc_loss_kernel_generic<<<dim3(B), dim3(THREADS), smem, stream>>>(
                ro, emb, nns, labels, nhn, loss_out, acc_out, E, Knns);
        }
    }
}

// Round 3
// 609.640 us; speedup vs baseline: 1.0245x; 1.0208x over previous
//
#include <hip/hip_runtime.h>
#include <math.h>

#define THREADS 256

// ---------------- K1: build per-vocab linked lists of (b,k) refs ------------
// rid = b*Knns + k encodes the ref. head[v] / next[rid] chains, built with
// atomicExch (set per v is deterministic; order irrelevant to outputs).
__global__ __launch_bounds__(THREADS) void build_lists_kernel(
    const int* __restrict__ nns,
    const int* __restrict__ labels,
    const int* __restrict__ nhn_ptr,
    int* __restrict__ head,
    int* __restrict__ next,
    int B, int Knns)
{
    const int rid = blockIdx.x * THREADS + threadIdx.x;
    if (rid >= B * Knns) return;
    const int b = (unsigned)rid / (unsigned)Knns;
    const int k = rid - b * Knns;
    const int K = nhn_ptr[0] + 1;
    if (k >= K) return;
    const int v = nns[(size_t)labels[b] * Knns + k];
    const int old = atomicExch(&head[v], rid);
    next[rid] = old;
}

// ---------------- K2: per-row 1/||ro|| and acc ------------------------------
__global__ __launch_bounds__(THREADS) void row_norm_kernel(
    const float* __restrict__ ro_g,
    float* __restrict__ invn,
    float* __restrict__ acc_out,
    int E)
{
    const int b = blockIdx.x, tid = threadIdx.x, lane = tid & 63, wave = tid >> 6;
    const int E4 = E >> 2;
    __shared__ float s_sum[4], s_max[4];
    const float4* ro4 = (const float4*)(ro_g + (size_t)b * E);
    float lsum = 0.f, lmax = -INFINITY;
    for (int i = tid; i < E4; i += THREADS) {
        float4 v = ro4[i];
        lsum += v.x * v.x + v.y * v.y + v.z * v.z + v.w * v.w;
        lmax = fmaxf(lmax, fmaxf(fmaxf(v.x, v.y), fmaxf(v.z, v.w)));
    }
    for (int m = 32; m; m >>= 1) {
        lsum += __shfl_xor(lsum, m, 64);
        lmax = fmaxf(lmax, __shfl_xor(lmax, m, 64));
    }
    if (lane == 0) { s_sum[wave] = lsum; s_max[wave] = lmax; }
    __syncthreads();
    if (tid == 0) {
        float t = 0.f, mx = -INFINITY;
        for (int w = 0; w < 4; ++w) { t += s_sum[w]; mx = fmaxf(mx, s_max[w]); }
        invn[b] = 1.0f / sqrtf(t);
        // argmax(ro_norm)==0  <=>  ro[b,0] >= rowmax (first-occurrence ties)
        acc_out[b] = (ro_g[(size_t)b * E] >= mx) ? 1.0f : 0.0f;
    }
}

// ---------------- K3: inverted gather-dot -----------------------------------
// One wave per vocab row v. emb[v] is read from HBM exactly once into
// registers (NCHUNK float4/lane, NCHUNK=E/256); the chain's ro rows (8 MB
// total working set) come from L2/L3.
template <int NCHUNK>
__global__ __launch_bounds__(THREADS) void gather_dot_kernel(
    const float* __restrict__ emb,
    const float* __restrict__ ro_g,
    const float* __restrict__ invn,
    const int* __restrict__ head,
    const int* __restrict__ next,
    float* __restrict__ scores,
    int V, int E, int Knns)
{
    const int lane = threadIdx.x & 63;
    const int wave = threadIdx.x >> 6;
    const int v = blockIdx.x * 4 + wave;
    if (v >= V) return;
    int i = head[v];
    if (i < 0) return;

    const float4* e4 = (const float4*)(emb + (size_t)v * E);
    float4 r[NCHUNK];
#pragma unroll
    for (int c = 0; c < NCHUNK; ++c) r[c] = e4[lane + 64 * c];

    while (i >= 0) {
        const int inext = next[i];                    // issue chase early
        const int b = (unsigned)i / (unsigned)Knns;
        const float4* ro4 = (const float4*)(ro_g + (size_t)b * E);
        float acc = 0.f;
#pragma unroll
        for (int c = 0; c < NCHUNK; ++c) {
            float4 x = ro4[lane + 64 * c];
            float4 rc = r[c];
            acc += x.x * rc.x + x.y * rc.y + x.z * rc.z + x.w * rc.w;
        }
        for (int m = 32; m; m >>= 1) acc += __shfl_xor(acc, m, 64);
        if (lane == 0) scores[i] = acc * invn[b];
        i = inext;
    }
}

// Generic-E fallback: same inversion, emb re-read per ref (L1-hot).
__global__ __launch_bounds__(THREADS) void gather_dot_generic(
    const float* __restrict__ emb,
    const float* __restrict__ ro_g,
    const float* __restrict__ invn,
    const int* __restrict__ head,
    const int* __restrict__ next,
    float* __restrict__ scores,
    int V, int E, int Knns)
{
    const int lane = threadIdx.x & 63;
    const int wave = threadIdx.x >> 6;
    const int v = blockIdx.x * 4 + wave;
    if (v >= V) return;
    int i = head[v];
    if (i < 0) return;
    const int E4 = E >> 2;
    const float4* e4 = (const float4*)(emb + (size_t)v * E);
    while (i >= 0) {
        const int inext = next[i];
        const int b = (unsigned)i / (unsigned)Knns;
        const float4* ro4 = (const float4*)(ro_g + (size_t)b * E);
        float acc = 0.f;
        for (int j = lane; j < E4; j += 64) {
            float4 x = ro4[j], e = e4[j];
            acc += x.x * e.x + x.y * e.y + x.z * e.z + x.w * e.w;
        }
        for (int m = 32; m; m >>= 1) acc += __shfl_xor(acc, m, 64);
        if (lane == 0) scores[i] = acc * invn[b];
        i = inext;
    }
}

// ---------------- K4: per-row logsumexp -> loss -----------------------------
__global__ __launch_bounds__(THREADS) void loss_kernel(
    const float* __restrict__ scores,
    const int* __restrict__ nhn_ptr,
    float* __restrict__ loss_out,
    int B, int Knns)
{
    const int lane = threadIdx.x & 63;
    const int wave = threadIdx.x >> 6;
    const int b = blockIdx.x * 4 + wave;
    if (b >= B) return;
    const int K = nhn_ptr[0] + 1;
    const float* s = scores + (size_t)b * Knns;
    float m = -INFINITY;
    for (int k = lane; k < K; k += 64) m = fmaxf(m, s[k]);
    for (int mm = 32; mm; mm >>= 1) m = fmaxf(m, __shfl_xor(m, mm, 64));
    float e = 0.f;
    for (int k = lane; k < K; k += 64) e += expf(s[k] - m);
    for (int mm = 32; mm; mm >>= 1) e += __shfl_xor(e, mm, 64);
    if (lane == 0) loss_out[b] = logf(e) + m - s[0];
}

extern "C" void kernel_launch(void* const* d_in, const int* in_sizes, int n_in,
                              void* d_out, int out_size, void* d_ws, size_t ws_size,
                              hipStream_t stream) {
    const float* ro     = (const float*)d_in[0];
    const float* emb    = (const float*)d_in[1];
    const int*   nns    = (const int*)d_in[2];
    const int*   labels = (const int*)d_in[3];
    const int*   nhn    = (const int*)d_in[4];

    const int B    = in_sizes[3];                 // 2048
    const int E    = in_sizes[0] / B;             // 1024
    const int V    = in_sizes[1] / E;             // 100000
    const int Knns = in_sizes[2] / V;             // 128

    float* loss_out = (float*)d_out;
    float* acc_out  = loss_out + B;

    // Workspace layout (256B-aligned slices).
    char* ws = (char*)d_ws;
    auto align = [](size_t x) { return (x + 255) & ~(size_t)255; };
    int*   head   = (int*)ws;                         ws += align((size_t)V * 4);
    int*   next   = (int*)ws;                         ws += align((size_t)B * Knns * 4);
    float* invn   = (float*)ws;                       ws += align((size_t)B * 4);
    float* scores = (float*)ws;

    hipMemsetAsync(head, 0xFF, (size_t)V * sizeof(int), stream);   // head = -1

    const int nrefs = B * Knns;
    build_lists_kernel<<<dim3((nrefs + THREADS - 1) / THREADS), dim3(THREADS), 0, stream>>>(
        nns, labels, nhn, head, next, B, Knns);

    row_norm_kernel<<<dim3(B), dim3(THREADS), 0, stream>>>(ro, invn, acc_out, E);

    const int vblocks = (V + 3) / 4;
    const int nchunk = (E % 256 == 0) ? (E / 256) : 0;
    switch (nchunk) {
        case 1: gather_dot_kernel<1><<<dim3(vblocks), dim3(THREADS), 0, stream>>>(
                    emb, ro, invn, head, next, scores, V, E, Knns); break;
        case 2: gather_dot_kernel<2><<<dim3(vblocks), dim3(THREADS), 0, stream>>>(
                    emb, ro, invn, head, next, scores, V, E, Knns); break;
        case 4: gather_dot_kernel<4><<<dim3(vblocks), dim3(THREADS), 0, stream>>>(
                    emb, ro, invn, head, next, scores, V, E, Knns); break;
        case 8: gather_dot_kernel<8><<<dim3(vblocks), dim3(THREADS), 0, stream>>>(
                    emb, ro, invn, head, next, scores, V, E, Knns); break;
        default: gather_dot_generic<<<dim3(vblocks), dim3(THREADS), 0, stream>>>(
                    emb, ro, invn, head, next, scores, V, E, Knns);
    }

    loss_kernel<<<dim3((B + 3) / 4), dim3(THREADS), 0, stream>>>(
        scores, nhn, loss_out, B, Knns);
}